// Round 11
// baseline (1189.407 us; speedup 1.0000x reference)
//
#include <hip/hip_runtime.h>
#include <math.h>

#define NB 4
#define SEQ 1024
#define DIM 1024
#define NH 16
#define DHEAD 64
#define BUFN 4194304ULL
#define WHN  1048576ULL
#define LOG2E 1.4426950408889634f

typedef _Float16 f16x8 __attribute__((ext_vector_type(8)));
typedef _Float16 f16x4 __attribute__((ext_vector_type(4)));
typedef float    f32x4 __attribute__((ext_vector_type(4)));

#define MFMA16 __builtin_amdgcn_mfma_f32_16x16x32_f16

__device__ __forceinline__ void split4(const float4 v, f16x4& h, f16x4& l)
{
    const _Float16 h0=(_Float16)v.x, h1=(_Float16)v.y, h2=(_Float16)v.z, h3=(_Float16)v.w;
    h = (f16x4){h0, h1, h2, h3};
    l = (f16x4){(_Float16)((v.x-(float)h0)*2048.0f),
                (_Float16)((v.y-(float)h1)*2048.0f),
                (_Float16)((v.z-(float)h2)*2048.0f),
                (_Float16)((v.w-(float)h3)*2048.0f)};
}

// ---------------------------------------------------------------------------
// split helpers
// ---------------------------------------------------------------------------
__global__ __launch_bounds__(256)
void splitx_kernel(const float* __restrict__ xr, const float* __restrict__ xi,
                   _Float16* __restrict__ XS)
{
    const float* x = blockIdx.y ? xi : xr;
    _Float16* h = XS + (size_t)blockIdx.y * 2 * BUFN;
    _Float16* l = h + BUFN;
    const int i = (blockIdx.x * 256 + threadIdx.x) << 2;
    const float4 v = *(const float4*)(x + i);
    f16x4 hh, ll; split4(v, hh, ll);
    *(f16x4*)(h + i) = hh;
    *(f16x4*)(l + i) = ll;
}

__global__ __launch_bounds__(256)
void splitw_kernel(const float* w0, const float* w1, const float* w2, const float* w3,
                   const float* w4, const float* w5, const float* w6, const float* w7,
                   _Float16* __restrict__ WS)
{
    const int y = blockIdx.y;
    const float* x = (y==0)?w0:(y==1)?w1:(y==2)?w2:(y==3)?w3:(y==4)?w4:(y==5)?w5:(y==6)?w6:w7;
    _Float16* h = WS + (size_t)y * 2 * WHN;
    _Float16* l = h + WHN;
    const int i = (blockIdx.x * 256 + threadIdx.x) << 2;
    float4 v = *(const float4*)(x + i);
    v.x *= 64.0f; v.y *= 64.0f; v.z *= 64.0f; v.w *= 64.0f;
    f16x4 hh, ll; split4(v, hh, ll);
    *(f16x4*)(h + i) = hh;
    *(f16x4*)(l + i) = ll;
}

// ---------------------------------------------------------------------------
// Complex GEMM on MFMA, fp16 2-way split. (r4 64x64 version, 0 bank conflicts)
// ---------------------------------------------------------------------------
template<int MODE>
__global__ __launch_bounds__(256, 1)
void cgemm16_kernel(const _Float16* __restrict__ Ahr, const _Float16* __restrict__ Alr,
                    const _Float16* __restrict__ Ahi, const _Float16* __restrict__ Ali,
                    const _Float16* __restrict__ Bhr, const _Float16* __restrict__ Blr,
                    const _Float16* __restrict__ Bhi, const _Float16* __restrict__ Bli,
                    float* __restrict__ outr, float* __restrict__ outi,
                    const float* __restrict__ resr, const float* __restrict__ resi,
                    float* __restrict__ msum, float scale)
{
    __shared__ __align__(16) _Float16 As[4][64][40];
    __shared__ __align__(16) _Float16 Bs[4][64][40];
    const int t    = threadIdx.x;
    const int lane = t & 63;
    const int w    = t >> 6;
    const int wm   = w >> 1, wn = w & 1;
    const int lr   = lane & 15;
    const int kc   = (lane >> 4) << 3;
    const int m0   = blockIdx.x * 64;
    const int o0   = blockIdx.y * 64;
    const int srow = t >> 2;
    const int sc8  = (t & 3) << 3;

    const size_t aoff = (size_t)(m0 + srow) * DIM + sc8;
    const size_t boff = (size_t)(o0 + srow) * DIM + sc8;

    f32x4 acc[2][2][4];
    #pragma unroll
    for (int i = 0; i < 2; ++i)
        #pragma unroll
        for (int j = 0; j < 2; ++j)
            #pragma unroll
            for (int c = 0; c < 4; ++c)
                acc[i][j][c] = (f32x4){0.f, 0.f, 0.f, 0.f};

    for (int k0 = 0; k0 < DIM; k0 += 32) {
        const uint4 va0 = *(const uint4*)(Ahr + aoff + k0);
        const uint4 va1 = *(const uint4*)(Alr + aoff + k0);
        const uint4 va2 = *(const uint4*)(Ahi + aoff + k0);
        const uint4 va3 = *(const uint4*)(Ali + aoff + k0);
        const uint4 vb0 = *(const uint4*)(Bhr + boff + k0);
        const uint4 vb1 = *(const uint4*)(Blr + boff + k0);
        const uint4 vb2 = *(const uint4*)(Bhi + boff + k0);
        const uint4 vb3 = *(const uint4*)(Bli + boff + k0);
        __syncthreads();
        *(uint4*)&As[0][srow][sc8] = va0;
        *(uint4*)&As[1][srow][sc8] = va1;
        *(uint4*)&As[2][srow][sc8] = va2;
        *(uint4*)&As[3][srow][sc8] = va3;
        *(uint4*)&Bs[0][srow][sc8] = vb0;
        *(uint4*)&Bs[1][srow][sc8] = vb1;
        *(uint4*)&Bs[2][srow][sc8] = vb2;
        *(uint4*)&Bs[3][srow][sc8] = vb3;
        __syncthreads();

        f16x8 a0[2], a1[2], a2[2], a3[2];
        #pragma unroll
        for (int mt = 0; mt < 2; ++mt) {
            const int ar = wm * 32 + mt * 16 + lr;
            a0[mt] = *(const f16x8*)&As[0][ar][kc];
            a1[mt] = *(const f16x8*)&As[1][ar][kc];
            a2[mt] = *(const f16x8*)&As[2][ar][kc];
            a3[mt] = *(const f16x8*)&As[3][ar][kc];
        }
        #pragma unroll
        for (int nt = 0; nt < 2; ++nt) {
            const int br = wn * 32 + nt * 16 + lr;
            const f16x8 bhr = *(const f16x8*)&Bs[0][br][kc];
            const f16x8 blr = *(const f16x8*)&Bs[1][br][kc];
            const f16x8 bhi = *(const f16x8*)&Bs[2][br][kc];
            const f16x8 bli = *(const f16x8*)&Bs[3][br][kc];
            const f16x8 bhiN = -bhi;
            const f16x8 bliN = -bli;
            #pragma unroll
            for (int mt = 0; mt < 2; ++mt) {
                acc[mt][nt][0] = MFMA16(a0[mt], bhr,  acc[mt][nt][0], 0, 0, 0);
                acc[mt][nt][0] = MFMA16(a2[mt], bhiN, acc[mt][nt][0], 0, 0, 0);
                acc[mt][nt][1] = MFMA16(a0[mt], blr,  acc[mt][nt][1], 0, 0, 0);
                acc[mt][nt][1] = MFMA16(a1[mt], bhr,  acc[mt][nt][1], 0, 0, 0);
                acc[mt][nt][1] = MFMA16(a2[mt], bliN, acc[mt][nt][1], 0, 0, 0);
                acc[mt][nt][1] = MFMA16(a3[mt], bhiN, acc[mt][nt][1], 0, 0, 0);
                acc[mt][nt][2] = MFMA16(a2[mt], bhr,  acc[mt][nt][2], 0, 0, 0);
                acc[mt][nt][2] = MFMA16(a0[mt], bhi,  acc[mt][nt][2], 0, 0, 0);
                acc[mt][nt][3] = MFMA16(a2[mt], blr,  acc[mt][nt][3], 0, 0, 0);
                acc[mt][nt][3] = MFMA16(a3[mt], bhr,  acc[mt][nt][3], 0, 0, 0);
                acc[mt][nt][3] = MFMA16(a0[mt], bli,  acc[mt][nt][3], 0, 0, 0);
                acc[mt][nt][3] = MFMA16(a1[mt], bhi,  acc[mt][nt][3], 0, 0, 0);
            }
        }
    }

    const float INVL = 1.0f / 2048.0f;
    if (MODE == 0) {
        #pragma unroll
        for (int mt = 0; mt < 2; ++mt)
            #pragma unroll
            for (int nt = 0; nt < 2; ++nt)
                #pragma unroll
                for (int r = 0; r < 4; ++r) {
                    const int mrow = m0 + wm * 32 + mt * 16 + ((lane >> 4)) * 4 + r;
                    const int ncol = o0 + wn * 32 + nt * 16 + lr;
                    const float cr = (acc[mt][nt][0][r] + acc[mt][nt][1][r] * INVL) * scale;
                    const float ci = (acc[mt][nt][2][r] + acc[mt][nt][3][r] * INVL) * scale;
                    const int b = mrow >> 10, s = mrow & 1023, h = ncol >> 6, dk = ncol & 63;
                    const size_t idx = (((size_t)b * NH + h) * SEQ + s) * DHEAD + dk;
                    outr[idx] = cr;
                    outi[idx] = ci;
                }
    } else {
        float sr = 0.f, si = 0.f;
        #pragma unroll
        for (int mt = 0; mt < 2; ++mt)
            #pragma unroll
            for (int nt = 0; nt < 2; ++nt)
                #pragma unroll
                for (int r = 0; r < 4; ++r) {
                    const int mrow = m0 + wm * 32 + mt * 16 + ((lane >> 4)) * 4 + r;
                    const int ncol = o0 + wn * 32 + nt * 16 + lr;
                    const size_t idx = (size_t)mrow * DIM + ncol;
                    const float cr = (acc[mt][nt][0][r] + acc[mt][nt][1][r] * INVL) * scale
                                     + resr[idx];
                    const float ci = (acc[mt][nt][2][r] + acc[mt][nt][3][r] * INVL) * scale
                                     + 1e-10f + resi[idx];
                    outr[idx] = cr;
                    outi[idx] = ci;
                    sr += cr; si += ci;
                }
        #pragma unroll
        for (int off = 32; off > 0; off >>= 1) { sr += __shfl_xor(sr, off); si += __shfl_xor(si, off); }
        __shared__ float wsum[8];
        if ((t & 63) == 0) { wsum[w * 2 + 0] = sr; wsum[w * 2 + 1] = si; }
        __syncthreads();
        if (t == 0) {
            atomicAdd(&msum[2 * (m0 >> 10) + 0], wsum[0] + wsum[2] + wsum[4] + wsum[6]);
            atomicAdd(&msum[2 * (m0 >> 10) + 1], wsum[1] + wsum[3] + wsum[5] + wsum[7]);
        }
    }
}

// ---------------------------------------------------------------------------
// V^T pre-transpose + split
// ---------------------------------------------------------------------------
__global__ __launch_bounds__(256)
void vtrans_kernel(const float* __restrict__ VR, const float* __restrict__ VI,
                   _Float16* __restrict__ Trh, _Float16* __restrict__ Trl,
                   _Float16* __restrict__ Tih, _Float16* __restrict__ Til)
{
    __shared__ float sr[64][68];
    __shared__ float si[64][68];
    const int t = threadIdx.x;
    const int kb = blockIdx.x, bh = blockIdx.y;
    const size_t ibase = (size_t)bh * SEQ * DHEAD + (size_t)kb * 64 * DHEAD;
    const int row = t >> 4, c0 = (t & 15) << 2;
    #pragma unroll
    for (int it = 0; it < 4; ++it) {
        const float4 a = *(const float4*)(VR + ibase + (size_t)(row + 16*it) * DHEAD + c0);
        const float4 b = *(const float4*)(VI + ibase + (size_t)(row + 16*it) * DHEAD + c0);
        *(float4*)&sr[row + 16*it][c0] = a;
        *(float4*)&si[row + 16*it][c0] = b;
    }
    __syncthreads();
    const int dk = t >> 2, k0 = (t & 3) << 4;
    f16x8 hr[2], lr8[2], hi8[2], li8[2];
    #pragma unroll
    for (int kk = 0; kk < 16; ++kk) {
        const float xr = sr[k0 + kk][dk];
        const float xi = si[k0 + kk][dk];
        const _Float16 hxr = (_Float16)xr;
        const _Float16 hxi = (_Float16)xi;
        hr[kk>>3][kk&7]  = hxr;
        lr8[kk>>3][kk&7] = (_Float16)((xr - (float)hxr) * 2048.0f);
        hi8[kk>>3][kk&7] = hxi;
        li8[kk>>3][kk&7] = (_Float16)((xi - (float)hxi) * 2048.0f);
    }
    const size_t ob = ((size_t)bh * 64 + dk) * SEQ + kb * 64 + k0;
    *(f16x8*)(Trh + ob) = hr[0];  *(f16x8*)(Trh + ob + 8) = hr[1];
    *(f16x8*)(Trl + ob) = lr8[0]; *(f16x8*)(Trl + ob + 8) = lr8[1];
    *(f16x8*)(Tih + ob) = hi8[0]; *(f16x8*)(Tih + ob + 8) = hi8[1];
    *(f16x8*)(Til + ob) = li8[0]; *(f16x8*)(Til + ob + 8) = li8[1];
}

// ---------------------------------------------------------------------------
// Scores: |Q.conj(K)^T| on MFMA. Q (once per block) split on the fly; K tiles
// staged as plain 16B copies from PRE-SPLIT planes (no per-kt split VALU).
// Magnitude via rsq (1 inst). Writes p~ = exp(s) + per-row L sums.
// ---------------------------------------------------------------------------
__global__ __launch_bounds__(256, 1)
void attn_scores_kernel(const float* __restrict__ QR, const float* __restrict__ QI,
                        const _Float16* __restrict__ KS,
                        float* __restrict__ attn, float* __restrict__ Lbuf)
{
    __shared__ __align__(16) _Float16 Ks[4][64][72];
    __shared__ float red[2][64];
    const int t = threadIdx.x;
    const int lane = t & 63;
    const int w = t >> 6, wm = w >> 1, wn = w & 1;
    const int lr = lane & 15, g = lane >> 4, kc = g << 3;
    const int q0 = blockIdx.x * 64;
    const int bh = blockIdx.y;
    const size_t base = (size_t)bh * SEQ * DHEAD;
    const int srow = t >> 2, sc0 = (t & 3) << 4;

    // stage Q (split once per block)
    #pragma unroll
    for (int c = 0; c < 4; ++c) {
        const float4 a = *(const float4*)(QR + base + (size_t)(q0 + srow) * DHEAD + sc0 + 4*c);
        const float4 b = *(const float4*)(QI + base + (size_t)(q0 + srow) * DHEAD + sc0 + 4*c);
        f16x4 h, l;
        split4(a, h, l);
        *(f16x4*)&Ks[0][srow][sc0 + 4*c] = h;
        *(f16x4*)&Ks[1][srow][sc0 + 4*c] = l;
        split4(b, h, l);
        *(f16x4*)&Ks[2][srow][sc0 + 4*c] = h;
        *(f16x4*)&Ks[3][srow][sc0 + 4*c] = l;
    }
    __syncthreads();
    f16x8 qhr[2][2], qlr[2][2], qhi[2][2], qli[2][2];
    #pragma unroll
    for (int mt = 0; mt < 2; ++mt) {
        const int row = wm * 32 + mt * 16 + lr;
        #pragma unroll
        for (int ks = 0; ks < 2; ++ks) {
            const int col = ks * 32 + kc;
            qhr[mt][ks] = *(const f16x8*)&Ks[0][row][col];
            qlr[mt][ks] = *(const f16x8*)&Ks[1][row][col];
            qhi[mt][ks] = *(const f16x8*)&Ks[2][row][col];
            qli[mt][ks] = *(const f16x8*)&Ks[3][row][col];
        }
    }

    float lsum[2][4] = {};
    // K prefetch: pre-split f16 planes, 2 x 16B per plane per thread
    uint4 pf[4][2];
    #pragma unroll
    for (int arr = 0; arr < 4; ++arr) {
        const _Float16* src = KS + arr * BUFN + base + (size_t)srow * DHEAD + sc0;
        pf[arr][0] = *(const uint4*)(src);
        pf[arr][1] = *(const uint4*)(src + 8);
    }

    for (int kt = 0; kt < 16; ++kt) {
        __syncthreads();
        #pragma unroll
        for (int arr = 0; arr < 4; ++arr) {
            *(uint4*)&Ks[arr][srow][sc0]     = pf[arr][0];
            *(uint4*)&Ks[arr][srow][sc0 + 8] = pf[arr][1];
        }
        __syncthreads();
        if (kt < 15) {
            const size_t koff = base + (size_t)((kt + 1) * 64 + srow) * DHEAD + sc0;
            #pragma unroll
            for (int arr = 0; arr < 4; ++arr) {
                const _Float16* src = KS + arr * BUFN + koff;
                pf[arr][0] = *(const uint4*)(src);
                pf[arr][1] = *(const uint4*)(src + 8);
            }
        }
        f32x4 arh[2][2], arl[2][2], aih[2][2], ail[2][2];
        #pragma unroll
        for (int i = 0; i < 2; ++i)
            #pragma unroll
            for (int j = 0; j < 2; ++j) {
                arh[i][j] = (f32x4){0,0,0,0}; arl[i][j] = (f32x4){0,0,0,0};
                aih[i][j] = (f32x4){0,0,0,0}; ail[i][j] = (f32x4){0,0,0,0};
            }
        #pragma unroll
        for (int nt = 0; nt < 2; ++nt) {
            const int brow = wn * 32 + nt * 16 + lr;
            #pragma unroll
            for (int ks = 0; ks < 2; ++ks) {
                const int col = ks * 32 + kc;
                const f16x8 khr = *(const f16x8*)&Ks[0][brow][col];
                const f16x8 klr = *(const f16x8*)&Ks[1][brow][col];
                const f16x8 khi = *(const f16x8*)&Ks[2][brow][col];
                const f16x8 kli = *(const f16x8*)&Ks[3][brow][col];
                const f16x8 khiN = -khi;
                const f16x8 kliN = -kli;
                #pragma unroll
                for (int mt = 0; mt < 2; ++mt) {
                    arh[mt][nt] = MFMA16(qhr[mt][ks], khr,  arh[mt][nt], 0,0,0);
                    arh[mt][nt] = MFMA16(qhi[mt][ks], khi,  arh[mt][nt], 0,0,0);
                    arl[mt][nt] = MFMA16(qhr[mt][ks], klr,  arl[mt][nt], 0,0,0);
                    arl[mt][nt] = MFMA16(qlr[mt][ks], khr,  arl[mt][nt], 0,0,0);
                    arl[mt][nt] = MFMA16(qhi[mt][ks], kli,  arl[mt][nt], 0,0,0);
                    arl[mt][nt] = MFMA16(qli[mt][ks], khi,  arl[mt][nt], 0,0,0);
                    aih[mt][nt] = MFMA16(qhi[mt][ks], khr,  aih[mt][nt], 0,0,0);
                    aih[mt][nt] = MFMA16(qhr[mt][ks], khiN, aih[mt][nt], 0,0,0);
                    ail[mt][nt] = MFMA16(qhi[mt][ks], klr,  ail[mt][nt], 0,0,0);
                    ail[mt][nt] = MFMA16(qli[mt][ks], khr,  ail[mt][nt], 0,0,0);
                    ail[mt][nt] = MFMA16(qhr[mt][ks], kliN, ail[mt][nt], 0,0,0);
                    ail[mt][nt] = MFMA16(qlr[mt][ks], khiN, ail[mt][nt], 0,0,0);
                }
            }
        }
        const float INV = 1.0f / 2048.0f;
        #pragma unroll
        for (int mt = 0; mt < 2; ++mt)
            #pragma unroll
            for (int nt = 0; nt < 2; ++nt)
                #pragma unroll
                for (int r = 0; r < 4; ++r) {
                    const float ar = arh[mt][nt][r] + arl[mt][nt][r] * INV;
                    const float ai = aih[mt][nt][r] + ail[mt][nt][r] * INV;
                    const float m2 = ar * ar + ai * ai;
                    const float s  = m2 * __frsqrt_rn(m2 + 1e-30f);
                    const float pp = exp2f(s * LOG2E);
                    const int q = q0 + wm * 32 + mt * 16 + g * 4 + r;
                    const int k = kt * 64 + wn * 32 + nt * 16 + lr;
                    attn[((size_t)bh * SEQ + q) * SEQ + k] = pp;   // p~ (unnormalized)
                    lsum[mt][r] += pp;
                }
    }
    #pragma unroll
    for (int mt = 0; mt < 2; ++mt)
        #pragma unroll
        for (int r = 0; r < 4; ++r) {
            float v = lsum[mt][r];
            v += __shfl_xor(v, 1); v += __shfl_xor(v, 2);
            v += __shfl_xor(v, 4); v += __shfl_xor(v, 8);
            lsum[mt][r] = v;
        }
    if (lr == 0) {
        #pragma unroll
        for (int mt = 0; mt < 2; ++mt)
            #pragma unroll
            for (int r = 0; r < 4; ++r)
                red[wn][wm * 32 + mt * 16 + g * 4 + r] = lsum[mt][r];
    }
    __syncthreads();
    if (t < 64) Lbuf[(size_t)bh * SEQ + q0 + t] = red[0][t] + red[1][t];
}

// ---------------------------------------------------------------------------
// PV (r10 version): reads p~, p = p~ * invL, writes final attn, PV on MFMA vs
// global-direct V^T, O as split-f16. kt-unrolled x2.
// ---------------------------------------------------------------------------
__global__ __launch_bounds__(256, 1)
void attn_pv_kernel(float* __restrict__ attn, const float* __restrict__ Lbuf,
                    const _Float16* __restrict__ Trh, const _Float16* __restrict__ Trl,
                    const _Float16* __restrict__ Tih, const _Float16* __restrict__ Til,
                    _Float16* __restrict__ XOhr, _Float16* __restrict__ XOlr,
                    _Float16* __restrict__ XOhi, _Float16* __restrict__ XOli)
{
    __shared__ __align__(16) _Float16 Psh[2][64][72];
    __shared__ __align__(16) _Float16 Psl[2][64][72];
    __shared__ float invL[64];
    const int t = threadIdx.x;
    const int lane = t & 63;
    const int w = t >> 6, wm = w >> 1, wn = w & 1;
    const int lr = lane & 15, g = lane >> 4, kc = g << 3;
    const int q0 = blockIdx.x * 64;
    const int bh = blockIdx.y;
    const size_t abase = ((size_t)bh * SEQ + q0) * SEQ;
    const size_t vbase = (size_t)bh * 64 * SEQ;

    if (t < 64) invL[t] = 1.0f / Lbuf[(size_t)bh * SEQ + q0 + t];

    const size_t voff[2] = { vbase + (size_t)(wn * 32 + lr) * SEQ + kc,
                             vbase + (size_t)(wn * 32 + 16 + lr) * SEQ + kc };

    f32x4 orh[2][2], orl[2][2], oih[2][2], oil[2][2];
    #pragma unroll
    for (int i = 0; i < 2; ++i)
        #pragma unroll
        for (int j = 0; j < 2; ++j) {
            orh[i][j] = (f32x4){0,0,0,0}; orl[i][j] = (f32x4){0,0,0,0};
            oih[i][j] = (f32x4){0,0,0,0}; oil[i][j] = (f32x4){0,0,0,0};
        }

    const int prow = t >> 4, pcol = (t & 15) << 2;
    float4 sc[2][4];
    #pragma unroll
    for (int u = 0; u < 2; ++u)
        #pragma unroll
        for (int it = 0; it < 4; ++it)
            sc[u][it] = *(const float4*)(attn + abase + (size_t)(prow + 16*it) * SEQ
                                         + u * 64 + pcol);

    for (int kp = 0; kp < 8; ++kp) {
        __syncthreads();
        #pragma unroll
        for (int u = 0; u < 2; ++u)
            #pragma unroll
            for (int it = 0; it < 4; ++it) {
                const int row = prow + 16*it;
                const float inv = invL[row];
                float4 p;
                p.x = sc[u][it].x * inv;
                p.y = sc[u][it].y * inv;
                p.z = sc[u][it].z * inv;
                p.w = sc[u][it].w * inv;
                *(float4*)(attn + abase + (size_t)row * SEQ + (kp*2 + u) * 64 + pcol) = p;
                float4 ps;
                ps.x = p.x * 1024.0f; ps.y = p.y * 1024.0f;
                ps.z = p.z * 1024.0f; ps.w = p.w * 1024.0f;
                f16x4 h, l; split4(ps, h, l);
                *(f16x4*)&Psh[u][row][pcol] = h;
                *(f16x4*)&Psl[u][row][pcol] = l;
            }
        __syncthreads();
        if (kp < 7) {
            #pragma unroll
            for (int u = 0; u < 2; ++u)
                #pragma unroll
                for (int it = 0; it < 4; ++it)
                    sc[u][it] = *(const float4*)(attn + abase + (size_t)(prow + 16*it) * SEQ
                                                 + (kp*2 + 2 + u) * 64 + pcol);
        }
        #pragma unroll
        for (int u = 0; u < 2; ++u) {
            #pragma unroll
            for (int ks = 0; ks < 2; ++ks) {
                const int col = ks * 32 + kc;
                f16x8 ph[2], pl[2];
                #pragma unroll
                for (int mt = 0; mt < 2; ++mt) {
                    const int row = wm * 32 + mt * 16 + lr;
                    ph[mt] = *(const f16x8*)&Psh[u][row][col];
                    pl[mt] = *(const f16x8*)&Psl[u][row][col];
                }
                const size_t vcol = (size_t)((kp*2 + u) * 64 + ks * 32);
                #pragma unroll
                for (int nt = 0; nt < 2; ++nt) {
                    const size_t vo = voff[nt] + vcol;
                    const f16x8 vhr = *(const f16x8*)(Trh + vo);
                    const f16x8 vlr = *(const f16x8*)(Trl + vo);
                    const f16x8 vhi = *(const f16x8*)(Tih + vo);
                    const f16x8 vli = *(const f16x8*)(Til + vo);
                    #pragma unroll
                    for (int mt = 0; mt < 2; ++mt) {
                        orh[mt][nt] = MFMA16(ph[mt], vhr, orh[mt][nt], 0,0,0);
                        orl[mt][nt] = MFMA16(ph[mt], vlr, orl[mt][nt], 0,0,0);
                        orl[mt][nt] = MFMA16(pl[mt], vhr, orl[mt][nt], 0,0,0);
                        oih[mt][nt] = MFMA16(ph[mt], vhi, oih[mt][nt], 0,0,0);
                        oil[mt][nt] = MFMA16(ph[mt], vli, oil[mt][nt], 0,0,0);
                        oil[mt][nt] = MFMA16(pl[mt], vhi, oil[mt][nt], 0,0,0);
                    }
                }
            }
        }
    }
    const float IL = 1.0f / 2048.0f, SP = 1.0f / 1024.0f;
    const int b = bh >> 4, h = bh & 15;
    #pragma unroll
    for (int mt = 0; mt < 2; ++mt)
        #pragma unroll
        for (int nt = 0; nt < 2; ++nt)
            #pragma unroll
            for (int r = 0; r < 4; ++r) {
                const float orv = (orh[mt][nt][r] + orl[mt][nt][r] * IL) * SP;
                const float oiv = (oih[mt][nt][r] + oil[mt][nt][r] * IL) * SP;
                const int q  = q0 + wm * 32 + mt * 16 + g * 4 + r;
                const int dk = wn * 32 + nt * 16 + lr;
                const size_t addr = ((size_t)b * SEQ + q) * DIM + h * DHEAD + dk;
                _Float16 hh = (_Float16)orv;
                XOhr[addr] = hh;
                XOlr[addr] = (_Float16)((orv - (float)hh) * 2048.0f);
                hh = (_Float16)oiv;
                XOhi[addr] = hh;
                XOli[addr] = (_Float16)((oiv - (float)hh) * 2048.0f);
            }
}

// ---------------------------------------------------------------------------
// ComplexLayerNorm elementwise pass
// ---------------------------------------------------------------------------
__global__ __launch_bounds__(256)
void ln_kernel(const float* __restrict__ xr, const float* __restrict__ xi,
               const float* __restrict__ msum, const float* __restrict__ gamma,
               const float* __restrict__ beta,
               float* __restrict__ yr, float* __restrict__ yi)
{
    const int gid = blockIdx.x * 256 + threadIdx.x;
    const int flat = gid << 2;
    const int b = flat >> 20;
    const int d = flat & (DIM - 1);
    const float mr = msum[2*b+0] * (1.0f/1048576.0f);
    const float mi = msum[2*b+1] * (1.0f/1048576.0f);
    const float4 vr = *(const float4*)(xr + flat);
    const float4 vi = *(const float4*)(xi + flat);
    const float4 g  = *(const float4*)(gamma + d);
    const float4 bt = *(const float4*)(beta + d);
    float4 or4, oi4;
    {
        float cr = vr.x - mr, ci = vi.x - mi;
        float inv = 1.0f / sqrtf(cr*cr + ci*ci + 1e-6f);
        or4.x = g.x * (cr * inv) + bt.x; oi4.x = g.x * (ci * inv);
    }
    {
        float cr = vr.y - mr, ci = vi.y - mi;
        float inv = 1.0f / sqrtf(cr*cr + ci*ci + 1e-6f);
        or4.y = g.y * (cr * inv) + bt.y; oi4.y = g.y * (ci * inv);
    }
    {
        float cr = vr.z - mr, ci = vi.z - mi;
        float inv = 1.0f / sqrtf(cr*cr + ci*ci + 1e-6f);
        or4.z = g.z * (cr * inv) + bt.z; oi4.z = g.z * (ci * inv);
    }
    {
        float cr = vr.w - mr, ci = vi.w - mi;
        float inv = 1.0f / sqrtf(cr*cr + ci*ci + 1e-6f);
        or4.w = g.w * (cr * inv) + bt.w; oi4.w = g.w * (ci * inv);
    }
    *(float4*)(yr + flat) = or4;
    *(float4*)(yi + flat) = oi4;
}

// ---------------------------------------------------------------------------
extern "C" void kernel_launch(void* const* d_in, const int* in_sizes, int n_in,
                              void* d_out, int out_size, void* d_ws, size_t ws_size,
                              hipStream_t stream)
{
    const float* q_r   = (const float*)d_in[0];
    const float* q_i   = (const float*)d_in[1];
    const float* k_r   = (const float*)d_in[2];
    const float* k_i   = (const float*)d_in[3];
    const float* v_r   = (const float*)d_in[4];
    const float* v_i   = (const float*)d_in[5];
    const float* wq_r  = (const float*)d_in[6];
    const float* wq_i  = (const float*)d_in[7];
    const float* wk_r  = (const float*)d_in[8];
    const float* wk_i  = (const float*)d_in[9];
    const float* wv_r  = (const float*)d_in[10];
    const float* wv_i  = (const float*)d_in[11];
    const float* wfc_r = (const float*)d_in[12];
    const float* wfc_i = (const float*)d_in[13];
    const float* gamma = (const float*)d_in[14];
    const float* beta  = (const float*)d_in[15];

    float* ws = (float*)d_ws;
    const size_t BUF = BUFN;
    float* QR   = ws + 0*BUF;
    float* QI   = ws + 1*BUF;
    float* KR   = ws + 2*BUF;
    float* KI   = ws + 3*BUF;
    float* VR   = ws + 4*BUF;
    float* VI   = ws + 5*BUF;
    float* MSUM = ws + 6*BUF;
    float* LBUF = ws + 6*BUF + 16;
    _Float16* F  = (_Float16*)(ws + 6*BUF + 16 + 65536);
    _Float16* XS = F;                 // 4 x BUF f16 (cgemm A-side / fc input)
    _Float16* VT = F + 4*BUF;         // 4 x BUF f16 (V^T split)
    _Float16* KSp = F + 8*BUF;        // 4 x BUF f16 (pre-split K, head layout)
    _Float16* WSp = F + 12*BUF;       // 16 x WHN f16 (weight splits)
    float* XR = QR;
    float* XI = QI;

    float* yr   = (float*)d_out;
    float* yi   = yr + BUF;
    float* attn = yr + 2*BUF;

    const dim3 blk(256);
    const dim3 g_gemm(64, 16);
    const float IWS = 1.0f / 64.0f;

    splitw_kernel<<<dim3(1024, 8), blk, 0, stream>>>(wq_r, wq_i, wk_r, wk_i,
                                                     wv_r, wv_i, wfc_r, wfc_i, WSp);

    splitx_kernel<<<dim3(4096, 2), blk, 0, stream>>>(q_r, q_i, XS);
    cgemm16_kernel<0><<<g_gemm, blk, 0, stream>>>(
        XS + 0*BUF, XS + 1*BUF, XS + 2*BUF, XS + 3*BUF,
        WSp + 0*WHN, WSp + 1*WHN, WSp + 2*WHN, WSp + 3*WHN,
        QR, QI, nullptr, nullptr, nullptr, 0.125f * IWS);

    splitx_kernel<<<dim3(4096, 2), blk, 0, stream>>>(k_r, k_i, XS);
    cgemm16_kernel<0><<<g_gemm, blk, 0, stream>>>(
        XS + 0*BUF, XS + 1*BUF, XS + 2*BUF, XS + 3*BUF,
        WSp + 4*WHN, WSp + 5*WHN, WSp + 6*WHN, WSp + 7*WHN,
        KR, KI, nullptr, nullptr, nullptr, IWS);

    // pre-split K (head-layout is linear; elementwise split is layout-agnostic)
    splitx_kernel<<<dim3(4096, 2), blk, 0, stream>>>(KR, KI, KSp);

    splitx_kernel<<<dim3(4096, 2), blk, 0, stream>>>(v_r, v_i, XS);
    cgemm16_kernel<0><<<g_gemm, blk, 0, stream>>>(
        XS + 0*BUF, XS + 1*BUF, XS + 2*BUF, XS + 3*BUF,
        WSp + 8*WHN, WSp + 9*WHN, WSp + 10*WHN, WSp + 11*WHN,
        VR, VI, nullptr, nullptr, nullptr, IWS);

    vtrans_kernel<<<dim3(16, 64), blk, 0, stream>>>(VR, VI,
        VT + 0*BUF, VT + 1*BUF, VT + 2*BUF, VT + 3*BUF);

    attn_scores_kernel<<<dim3(16, 64), blk, 0, stream>>>(QR, QI, KSp, attn, LBUF);

    attn_pv_kernel<<<dim3(16, 64), blk, 0, stream>>>(attn, LBUF,
        VT + 0*BUF, VT + 1*BUF, VT + 2*BUF, VT + 3*BUF,
        XS + 0*BUF, XS + 1*BUF, XS + 2*BUF, XS + 3*BUF);

    hipMemsetAsync(MSUM, 0, 8 * sizeof(float), stream);
    cgemm16_kernel<1><<<g_gemm, blk, 0, stream>>>(
        XS + 0*BUF, XS + 1*BUF, XS + 2*BUF, XS + 3*BUF,
        WSp + 12*WHN, WSp + 13*WHN, WSp + 14*WHN, WSp + 15*WHN,
        XR, XI, q_r, q_i, MSUM, IWS);
    ln_kernel<<<dim3(4096), blk, 0, stream>>>(XR, XI, MSUM, gamma, beta, yr, yi);
}

// Round 12
// 989.242 us; speedup vs baseline: 1.2023x; 1.2023x over previous
//
#include <hip/hip_runtime.h>
#include <math.h>

#define NB 4
#define SEQ 1024
#define DIM 1024
#define NH 16
#define DHEAD 64
#define BUFN 4194304ULL
#define WHN  1048576ULL
#define LOG2E 1.4426950408889634f

typedef _Float16 f16x8 __attribute__((ext_vector_type(8)));
typedef _Float16 f16x4 __attribute__((ext_vector_type(4)));
typedef float    f32x4 __attribute__((ext_vector_type(4)));

#define MFMA16 __builtin_amdgcn_mfma_f32_16x16x32_f16

__device__ __forceinline__ void split4(const float4 v, f16x4& h, f16x4& l)
{
    const _Float16 h0=(_Float16)v.x, h1=(_Float16)v.y, h2=(_Float16)v.z, h3=(_Float16)v.w;
    h = (f16x4){h0, h1, h2, h3};
    l = (f16x4){(_Float16)((v.x-(float)h0)*2048.0f),
                (_Float16)((v.y-(float)h1)*2048.0f),
                (_Float16)((v.z-(float)h2)*2048.0f),
                (_Float16)((v.w-(float)h3)*2048.0f)};
}

// ---------------------------------------------------------------------------
// split helpers
// ---------------------------------------------------------------------------
__global__ __launch_bounds__(256)
void splitx_kernel(const float* __restrict__ xr, const float* __restrict__ xi,
                   _Float16* __restrict__ XS)
{
    const float* x = blockIdx.y ? xi : xr;
    _Float16* h = XS + (size_t)blockIdx.y * 2 * BUFN;
    _Float16* l = h + BUFN;
    const int i = (blockIdx.x * 256 + threadIdx.x) << 2;
    const float4 v = *(const float4*)(x + i);
    f16x4 hh, ll; split4(v, hh, ll);
    *(f16x4*)(h + i) = hh;
    *(f16x4*)(l + i) = ll;
}

__global__ __launch_bounds__(256)
void splitw_kernel(const float* w0, const float* w1, const float* w2, const float* w3,
                   const float* w4, const float* w5, const float* w6, const float* w7,
                   _Float16* __restrict__ WS)
{
    const int y = blockIdx.y;
    const float* x = (y==0)?w0:(y==1)?w1:(y==2)?w2:(y==3)?w3:(y==4)?w4:(y==5)?w5:(y==6)?w6:w7;
    _Float16* h = WS + (size_t)y * 2 * WHN;
    _Float16* l = h + WHN;
    const int i = (blockIdx.x * 256 + threadIdx.x) << 2;
    float4 v = *(const float4*)(x + i);
    v.x *= 64.0f; v.y *= 64.0f; v.z *= 64.0f; v.w *= 64.0f;
    f16x4 hh, ll; split4(v, hh, ll);
    *(f16x4*)(h + i) = hh;
    *(f16x4*)(l + i) = ll;
}

// ---------------------------------------------------------------------------
// Complex GEMM on MFMA, fp16 2-way split. (r4 64x64 version, 0 bank conflicts)
// ---------------------------------------------------------------------------
template<int MODE>
__global__ __launch_bounds__(256, 1)
void cgemm16_kernel(const _Float16* __restrict__ Ahr, const _Float16* __restrict__ Alr,
                    const _Float16* __restrict__ Ahi, const _Float16* __restrict__ Ali,
                    const _Float16* __restrict__ Bhr, const _Float16* __restrict__ Blr,
                    const _Float16* __restrict__ Bhi, const _Float16* __restrict__ Bli,
                    float* __restrict__ outr, float* __restrict__ outi,
                    const float* __restrict__ resr, const float* __restrict__ resi,
                    float* __restrict__ msum, float scale)
{
    __shared__ __align__(16) _Float16 As[4][64][40];
    __shared__ __align__(16) _Float16 Bs[4][64][40];
    const int t    = threadIdx.x;
    const int lane = t & 63;
    const int w    = t >> 6;
    const int wm   = w >> 1, wn = w & 1;
    const int lr   = lane & 15;
    const int kc   = (lane >> 4) << 3;
    const int m0   = blockIdx.x * 64;
    const int o0   = blockIdx.y * 64;
    const int srow = t >> 2;
    const int sc8  = (t & 3) << 3;

    const size_t aoff = (size_t)(m0 + srow) * DIM + sc8;
    const size_t boff = (size_t)(o0 + srow) * DIM + sc8;

    f32x4 acc[2][2][4];
    #pragma unroll
    for (int i = 0; i < 2; ++i)
        #pragma unroll
        for (int j = 0; j < 2; ++j)
            #pragma unroll
            for (int c = 0; c < 4; ++c)
                acc[i][j][c] = (f32x4){0.f, 0.f, 0.f, 0.f};

    for (int k0 = 0; k0 < DIM; k0 += 32) {
        const uint4 va0 = *(const uint4*)(Ahr + aoff + k0);
        const uint4 va1 = *(const uint4*)(Alr + aoff + k0);
        const uint4 va2 = *(const uint4*)(Ahi + aoff + k0);
        const uint4 va3 = *(const uint4*)(Ali + aoff + k0);
        const uint4 vb0 = *(const uint4*)(Bhr + boff + k0);
        const uint4 vb1 = *(const uint4*)(Blr + boff + k0);
        const uint4 vb2 = *(const uint4*)(Bhi + boff + k0);
        const uint4 vb3 = *(const uint4*)(Bli + boff + k0);
        __syncthreads();
        *(uint4*)&As[0][srow][sc8] = va0;
        *(uint4*)&As[1][srow][sc8] = va1;
        *(uint4*)&As[2][srow][sc8] = va2;
        *(uint4*)&As[3][srow][sc8] = va3;
        *(uint4*)&Bs[0][srow][sc8] = vb0;
        *(uint4*)&Bs[1][srow][sc8] = vb1;
        *(uint4*)&Bs[2][srow][sc8] = vb2;
        *(uint4*)&Bs[3][srow][sc8] = vb3;
        __syncthreads();

        f16x8 a0[2], a1[2], a2[2], a3[2];
        #pragma unroll
        for (int mt = 0; mt < 2; ++mt) {
            const int ar = wm * 32 + mt * 16 + lr;
            a0[mt] = *(const f16x8*)&As[0][ar][kc];
            a1[mt] = *(const f16x8*)&As[1][ar][kc];
            a2[mt] = *(const f16x8*)&As[2][ar][kc];
            a3[mt] = *(const f16x8*)&As[3][ar][kc];
        }
        #pragma unroll
        for (int nt = 0; nt < 2; ++nt) {
            const int br = wn * 32 + nt * 16 + lr;
            const f16x8 bhr = *(const f16x8*)&Bs[0][br][kc];
            const f16x8 blr = *(const f16x8*)&Bs[1][br][kc];
            const f16x8 bhi = *(const f16x8*)&Bs[2][br][kc];
            const f16x8 bli = *(const f16x8*)&Bs[3][br][kc];
            const f16x8 bhiN = -bhi;
            const f16x8 bliN = -bli;
            #pragma unroll
            for (int mt = 0; mt < 2; ++mt) {
                acc[mt][nt][0] = MFMA16(a0[mt], bhr,  acc[mt][nt][0], 0, 0, 0);
                acc[mt][nt][0] = MFMA16(a2[mt], bhiN, acc[mt][nt][0], 0, 0, 0);
                acc[mt][nt][1] = MFMA16(a0[mt], blr,  acc[mt][nt][1], 0, 0, 0);
                acc[mt][nt][1] = MFMA16(a1[mt], bhr,  acc[mt][nt][1], 0, 0, 0);
                acc[mt][nt][1] = MFMA16(a2[mt], bliN, acc[mt][nt][1], 0, 0, 0);
                acc[mt][nt][1] = MFMA16(a3[mt], bhiN, acc[mt][nt][1], 0, 0, 0);
                acc[mt][nt][2] = MFMA16(a2[mt], bhr,  acc[mt][nt][2], 0, 0, 0);
                acc[mt][nt][2] = MFMA16(a0[mt], bhi,  acc[mt][nt][2], 0, 0, 0);
                acc[mt][nt][3] = MFMA16(a2[mt], blr,  acc[mt][nt][3], 0, 0, 0);
                acc[mt][nt][3] = MFMA16(a3[mt], bhr,  acc[mt][nt][3], 0, 0, 0);
                acc[mt][nt][3] = MFMA16(a0[mt], bli,  acc[mt][nt][3], 0, 0, 0);
                acc[mt][nt][3] = MFMA16(a1[mt], bhi,  acc[mt][nt][3], 0, 0, 0);
            }
        }
    }

    const float INVL = 1.0f / 2048.0f;
    if (MODE == 0) {
        #pragma unroll
        for (int mt = 0; mt < 2; ++mt)
            #pragma unroll
            for (int nt = 0; nt < 2; ++nt)
                #pragma unroll
                for (int r = 0; r < 4; ++r) {
                    const int mrow = m0 + wm * 32 + mt * 16 + ((lane >> 4)) * 4 + r;
                    const int ncol = o0 + wn * 32 + nt * 16 + lr;
                    const float cr = (acc[mt][nt][0][r] + acc[mt][nt][1][r] * INVL) * scale;
                    const float ci = (acc[mt][nt][2][r] + acc[mt][nt][3][r] * INVL) * scale;
                    const int b = mrow >> 10, s = mrow & 1023, h = ncol >> 6, dk = ncol & 63;
                    const size_t idx = (((size_t)b * NH + h) * SEQ + s) * DHEAD + dk;
                    outr[idx] = cr;
                    outi[idx] = ci;
                }
    } else {
        float sr = 0.f, si = 0.f;
        #pragma unroll
        for (int mt = 0; mt < 2; ++mt)
            #pragma unroll
            for (int nt = 0; nt < 2; ++nt)
                #pragma unroll
                for (int r = 0; r < 4; ++r) {
                    const int mrow = m0 + wm * 32 + mt * 16 + ((lane >> 4)) * 4 + r;
                    const int ncol = o0 + wn * 32 + nt * 16 + lr;
                    const size_t idx = (size_t)mrow * DIM + ncol;
                    const float cr = (acc[mt][nt][0][r] + acc[mt][nt][1][r] * INVL) * scale
                                     + resr[idx];
                    const float ci = (acc[mt][nt][2][r] + acc[mt][nt][3][r] * INVL) * scale
                                     + 1e-10f + resi[idx];
                    outr[idx] = cr;
                    outi[idx] = ci;
                    sr += cr; si += ci;
                }
        #pragma unroll
        for (int off = 32; off > 0; off >>= 1) { sr += __shfl_xor(sr, off); si += __shfl_xor(si, off); }
        __shared__ float wsum[8];
        if ((t & 63) == 0) { wsum[w * 2 + 0] = sr; wsum[w * 2 + 1] = si; }
        __syncthreads();
        if (t == 0) {
            atomicAdd(&msum[2 * (m0 >> 10) + 0], wsum[0] + wsum[2] + wsum[4] + wsum[6]);
            atomicAdd(&msum[2 * (m0 >> 10) + 1], wsum[1] + wsum[3] + wsum[5] + wsum[7]);
        }
    }
}

// ---------------------------------------------------------------------------
// V^T pre-transpose + split
// ---------------------------------------------------------------------------
__global__ __launch_bounds__(256)
void vtrans_kernel(const float* __restrict__ VR, const float* __restrict__ VI,
                   _Float16* __restrict__ Trh, _Float16* __restrict__ Trl,
                   _Float16* __restrict__ Tih, _Float16* __restrict__ Til)
{
    __shared__ float sr[64][68];
    __shared__ float si[64][68];
    const int t = threadIdx.x;
    const int kb = blockIdx.x, bh = blockIdx.y;
    const size_t ibase = (size_t)bh * SEQ * DHEAD + (size_t)kb * 64 * DHEAD;
    const int row = t >> 4, c0 = (t & 15) << 2;
    #pragma unroll
    for (int it = 0; it < 4; ++it) {
        const float4 a = *(const float4*)(VR + ibase + (size_t)(row + 16*it) * DHEAD + c0);
        const float4 b = *(const float4*)(VI + ibase + (size_t)(row + 16*it) * DHEAD + c0);
        *(float4*)&sr[row + 16*it][c0] = a;
        *(float4*)&si[row + 16*it][c0] = b;
    }
    __syncthreads();
    const int dk = t >> 2, k0 = (t & 3) << 4;
    f16x8 hr[2], lr8[2], hi8[2], li8[2];
    #pragma unroll
    for (int kk = 0; kk < 16; ++kk) {
        const float xr = sr[k0 + kk][dk];
        const float xi = si[k0 + kk][dk];
        const _Float16 hxr = (_Float16)xr;
        const _Float16 hxi = (_Float16)xi;
        hr[kk>>3][kk&7]  = hxr;
        lr8[kk>>3][kk&7] = (_Float16)((xr - (float)hxr) * 2048.0f);
        hi8[kk>>3][kk&7] = hxi;
        li8[kk>>3][kk&7] = (_Float16)((xi - (float)hxi) * 2048.0f);
    }
    const size_t ob = ((size_t)bh * 64 + dk) * SEQ + kb * 64 + k0;
    *(f16x8*)(Trh + ob) = hr[0];  *(f16x8*)(Trh + ob + 8) = hr[1];
    *(f16x8*)(Trl + ob) = lr8[0]; *(f16x8*)(Trl + ob + 8) = lr8[1];
    *(f16x8*)(Tih + ob) = hi8[0]; *(f16x8*)(Tih + ob + 8) = hi8[1];
    *(f16x8*)(Til + ob) = li8[0]; *(f16x8*)(Til + ob + 8) = li8[1];
}

// ---------------------------------------------------------------------------
// Scores (r10 structure): |Q.conj(K)^T| on MFMA, fp32 inputs split on the fly
// into LDS (8B conflict-free writes). Writes p~ = exp(s) + per-row L sums.
// CHANGE vs r10: magnitude via rsq (1 inst, validated in r11) instead of sqrtf.
// ---------------------------------------------------------------------------
__global__ __launch_bounds__(256, 1)
void attn_scores_kernel(const float* __restrict__ QR, const float* __restrict__ QI,
                        const float* __restrict__ KR, const float* __restrict__ KI,
                        float* __restrict__ attn, float* __restrict__ Lbuf)
{
    __shared__ __align__(16) _Float16 Ks[4][64][72];
    __shared__ float red[2][64];
    const int t = threadIdx.x;
    const int lane = t & 63;
    const int w = t >> 6, wm = w >> 1, wn = w & 1;
    const int lr = lane & 15, g = lane >> 4, kc = g << 3;
    const int q0 = blockIdx.x * 64;
    const int bh = blockIdx.y;
    const size_t base = (size_t)bh * SEQ * DHEAD;
    const int srow = t >> 2, sc0 = (t & 3) << 4;

    #pragma unroll
    for (int c = 0; c < 4; ++c) {
        const float4 a = *(const float4*)(QR + base + (size_t)(q0 + srow) * DHEAD + sc0 + 4*c);
        const float4 b = *(const float4*)(QI + base + (size_t)(q0 + srow) * DHEAD + sc0 + 4*c);
        f16x4 h, l;
        split4(a, h, l);
        *(f16x4*)&Ks[0][srow][sc0 + 4*c] = h;
        *(f16x4*)&Ks[1][srow][sc0 + 4*c] = l;
        split4(b, h, l);
        *(f16x4*)&Ks[2][srow][sc0 + 4*c] = h;
        *(f16x4*)&Ks[3][srow][sc0 + 4*c] = l;
    }
    __syncthreads();
    f16x8 qhr[2][2], qlr[2][2], qhi[2][2], qli[2][2];
    #pragma unroll
    for (int mt = 0; mt < 2; ++mt) {
        const int row = wm * 32 + mt * 16 + lr;
        #pragma unroll
        for (int ks = 0; ks < 2; ++ks) {
            const int col = ks * 32 + kc;
            qhr[mt][ks] = *(const f16x8*)&Ks[0][row][col];
            qlr[mt][ks] = *(const f16x8*)&Ks[1][row][col];
            qhi[mt][ks] = *(const f16x8*)&Ks[2][row][col];
            qli[mt][ks] = *(const f16x8*)&Ks[3][row][col];
        }
    }

    float lsum[2][4] = {};
    float4 pr[4], pi4[4];
    #pragma unroll
    for (int c = 0; c < 4; ++c) {
        pr[c]  = *(const float4*)(KR + base + (size_t)srow * DHEAD + sc0 + 4*c);
        pi4[c] = *(const float4*)(KI + base + (size_t)srow * DHEAD + sc0 + 4*c);
    }

    for (int kt = 0; kt < 16; ++kt) {
        __syncthreads();
        #pragma unroll
        for (int c = 0; c < 4; ++c) {
            f16x4 h, l;
            split4(pr[c], h, l);
            *(f16x4*)&Ks[0][srow][sc0 + 4*c] = h;
            *(f16x4*)&Ks[1][srow][sc0 + 4*c] = l;
            split4(pi4[c], h, l);
            *(f16x4*)&Ks[2][srow][sc0 + 4*c] = h;
            *(f16x4*)&Ks[3][srow][sc0 + 4*c] = l;
        }
        __syncthreads();
        if (kt < 15) {
            const size_t koff = base + (size_t)((kt + 1) * 64 + srow) * DHEAD;
            #pragma unroll
            for (int c = 0; c < 4; ++c) {
                pr[c]  = *(const float4*)(KR + koff + sc0 + 4*c);
                pi4[c] = *(const float4*)(KI + koff + sc0 + 4*c);
            }
        }
        f32x4 arh[2][2], arl[2][2], aih[2][2], ail[2][2];
        #pragma unroll
        for (int i = 0; i < 2; ++i)
            #pragma unroll
            for (int j = 0; j < 2; ++j) {
                arh[i][j] = (f32x4){0,0,0,0}; arl[i][j] = (f32x4){0,0,0,0};
                aih[i][j] = (f32x4){0,0,0,0}; ail[i][j] = (f32x4){0,0,0,0};
            }
        #pragma unroll
        for (int nt = 0; nt < 2; ++nt) {
            const int brow = wn * 32 + nt * 16 + lr;
            #pragma unroll
            for (int ks = 0; ks < 2; ++ks) {
                const int col = ks * 32 + kc;
                const f16x8 khr = *(const f16x8*)&Ks[0][brow][col];
                const f16x8 klr = *(const f16x8*)&Ks[1][brow][col];
                const f16x8 khi = *(const f16x8*)&Ks[2][brow][col];
                const f16x8 kli = *(const f16x8*)&Ks[3][brow][col];
                const f16x8 khiN = -khi;
                const f16x8 kliN = -kli;
                #pragma unroll
                for (int mt = 0; mt < 2; ++mt) {
                    arh[mt][nt] = MFMA16(qhr[mt][ks], khr,  arh[mt][nt], 0,0,0);
                    arh[mt][nt] = MFMA16(qhi[mt][ks], khi,  arh[mt][nt], 0,0,0);
                    arl[mt][nt] = MFMA16(qhr[mt][ks], klr,  arl[mt][nt], 0,0,0);
                    arl[mt][nt] = MFMA16(qlr[mt][ks], khr,  arl[mt][nt], 0,0,0);
                    arl[mt][nt] = MFMA16(qhi[mt][ks], kli,  arl[mt][nt], 0,0,0);
                    arl[mt][nt] = MFMA16(qli[mt][ks], khi,  arl[mt][nt], 0,0,0);
                    aih[mt][nt] = MFMA16(qhi[mt][ks], khr,  aih[mt][nt], 0,0,0);
                    aih[mt][nt] = MFMA16(qhr[mt][ks], khiN, aih[mt][nt], 0,0,0);
                    ail[mt][nt] = MFMA16(qhi[mt][ks], klr,  ail[mt][nt], 0,0,0);
                    ail[mt][nt] = MFMA16(qli[mt][ks], khr,  ail[mt][nt], 0,0,0);
                    ail[mt][nt] = MFMA16(qhr[mt][ks], kliN, ail[mt][nt], 0,0,0);
                    ail[mt][nt] = MFMA16(qlr[mt][ks], khiN, ail[mt][nt], 0,0,0);
                }
            }
        }
        const float INV = 1.0f / 2048.0f;
        #pragma unroll
        for (int mt = 0; mt < 2; ++mt)
            #pragma unroll
            for (int nt = 0; nt < 2; ++nt)
                #pragma unroll
                for (int r = 0; r < 4; ++r) {
                    const float ar = arh[mt][nt][r] + arl[mt][nt][r] * INV;
                    const float ai = aih[mt][nt][r] + ail[mt][nt][r] * INV;
                    const float m2 = ar * ar + ai * ai;
                    const float s  = m2 * __frsqrt_rn(m2 + 1e-30f);
                    const float pp = exp2f(s * LOG2E);
                    const int q = q0 + wm * 32 + mt * 16 + g * 4 + r;
                    const int k = kt * 64 + wn * 32 + nt * 16 + lr;
                    attn[((size_t)bh * SEQ + q) * SEQ + k] = pp;   // p~ (unnormalized)
                    lsum[mt][r] += pp;
                }
    }
    #pragma unroll
    for (int mt = 0; mt < 2; ++mt)
        #pragma unroll
        for (int r = 0; r < 4; ++r) {
            float v = lsum[mt][r];
            v += __shfl_xor(v, 1); v += __shfl_xor(v, 2);
            v += __shfl_xor(v, 4); v += __shfl_xor(v, 8);
            lsum[mt][r] = v;
        }
    if (lr == 0) {
        #pragma unroll
        for (int mt = 0; mt < 2; ++mt)
            #pragma unroll
            for (int r = 0; r < 4; ++r)
                red[wn][wm * 32 + mt * 16 + g * 4 + r] = lsum[mt][r];
    }
    __syncthreads();
    if (t < 64) Lbuf[(size_t)bh * SEQ + q0 + t] = red[0][t] + red[1][t];
}

// ---------------------------------------------------------------------------
// PV (r10 version): reads p~, p = p~ * invL, writes final attn, PV on MFMA vs
// global-direct V^T, O as split-f16. kt-unrolled x2.
// ---------------------------------------------------------------------------
__global__ __launch_bounds__(256, 1)
void attn_pv_kernel(float* __restrict__ attn, const float* __restrict__ Lbuf,
                    const _Float16* __restrict__ Trh, const _Float16* __restrict__ Trl,
                    const _Float16* __restrict__ Tih, const _Float16* __restrict__ Til,
                    _Float16* __restrict__ XOhr, _Float16* __restrict__ XOlr,
                    _Float16* __restrict__ XOhi, _Float16* __restrict__ XOli)
{
    __shared__ __align__(16) _Float16 Psh[2][64][72];
    __shared__ __align__(16) _Float16 Psl[2][64][72];
    __shared__ float invL[64];
    const int t = threadIdx.x;
    const int lane = t & 63;
    const int w = t >> 6, wm = w >> 1, wn = w & 1;
    const int lr = lane & 15, g = lane >> 4, kc = g << 3;
    const int q0 = blockIdx.x * 64;
    const int bh = blockIdx.y;
    const size_t abase = ((size_t)bh * SEQ + q0) * SEQ;
    const size_t vbase = (size_t)bh * 64 * SEQ;

    if (t < 64) invL[t] = 1.0f / Lbuf[(size_t)bh * SEQ + q0 + t];

    const size_t voff[2] = { vbase + (size_t)(wn * 32 + lr) * SEQ + kc,
                             vbase + (size_t)(wn * 32 + 16 + lr) * SEQ + kc };

    f32x4 orh[2][2], orl[2][2], oih[2][2], oil[2][2];
    #pragma unroll
    for (int i = 0; i < 2; ++i)
        #pragma unroll
        for (int j = 0; j < 2; ++j) {
            orh[i][j] = (f32x4){0,0,0,0}; orl[i][j] = (f32x4){0,0,0,0};
            oih[i][j] = (f32x4){0,0,0,0}; oil[i][j] = (f32x4){0,0,0,0};
        }

    const int prow = t >> 4, pcol = (t & 15) << 2;
    float4 sc[2][4];
    #pragma unroll
    for (int u = 0; u < 2; ++u)
        #pragma unroll
        for (int it = 0; it < 4; ++it)
            sc[u][it] = *(const float4*)(attn + abase + (size_t)(prow + 16*it) * SEQ
                                         + u * 64 + pcol);

    for (int kp = 0; kp < 8; ++kp) {
        __syncthreads();
        #pragma unroll
        for (int u = 0; u < 2; ++u)
            #pragma unroll
            for (int it = 0; it < 4; ++it) {
                const int row = prow + 16*it;
                const float inv = invL[row];
                float4 p;
                p.x = sc[u][it].x * inv;
                p.y = sc[u][it].y * inv;
                p.z = sc[u][it].z * inv;
                p.w = sc[u][it].w * inv;
                *(float4*)(attn + abase + (size_t)row * SEQ + (kp*2 + u) * 64 + pcol) = p;
                float4 ps;
                ps.x = p.x * 1024.0f; ps.y = p.y * 1024.0f;
                ps.z = p.z * 1024.0f; ps.w = p.w * 1024.0f;
                f16x4 h, l; split4(ps, h, l);
                *(f16x4*)&Psh[u][row][pcol] = h;
                *(f16x4*)&Psl[u][row][pcol] = l;
            }
        __syncthreads();
        if (kp < 7) {
            #pragma unroll
            for (int u = 0; u < 2; ++u)
                #pragma unroll
                for (int it = 0; it < 4; ++it)
                    sc[u][it] = *(const float4*)(attn + abase + (size_t)(prow + 16*it) * SEQ
                                                 + (kp*2 + 2 + u) * 64 + pcol);
        }
        #pragma unroll
        for (int u = 0; u < 2; ++u) {
            #pragma unroll
            for (int ks = 0; ks < 2; ++ks) {
                const int col = ks * 32 + kc;
                f16x8 ph[2], pl[2];
                #pragma unroll
                for (int mt = 0; mt < 2; ++mt) {
                    const int row = wm * 32 + mt * 16 + lr;
                    ph[mt] = *(const f16x8*)&Psh[u][row][col];
                    pl[mt] = *(const f16x8*)&Psl[u][row][col];
                }
                const size_t vcol = (size_t)((kp*2 + u) * 64 + ks * 32);
                #pragma unroll
                for (int nt = 0; nt < 2; ++nt) {
                    const size_t vo = voff[nt] + vcol;
                    const f16x8 vhr = *(const f16x8*)(Trh + vo);
                    const f16x8 vlr = *(const f16x8*)(Trl + vo);
                    const f16x8 vhi = *(const f16x8*)(Tih + vo);
                    const f16x8 vli = *(const f16x8*)(Til + vo);
                    #pragma unroll
                    for (int mt = 0; mt < 2; ++mt) {
                        orh[mt][nt] = MFMA16(ph[mt], vhr, orh[mt][nt], 0,0,0);
                        orl[mt][nt] = MFMA16(ph[mt], vlr, orl[mt][nt], 0,0,0);
                        orl[mt][nt] = MFMA16(pl[mt], vhr, orl[mt][nt], 0,0,0);
                        oih[mt][nt] = MFMA16(ph[mt], vhi, oih[mt][nt], 0,0,0);
                        oil[mt][nt] = MFMA16(ph[mt], vli, oil[mt][nt], 0,0,0);
                        oil[mt][nt] = MFMA16(pl[mt], vhi, oil[mt][nt], 0,0,0);
                    }
                }
            }
        }
    }
    const float IL = 1.0f / 2048.0f, SP = 1.0f / 1024.0f;
    const int b = bh >> 4, h = bh & 15;
    #pragma unroll
    for (int mt = 0; mt < 2; ++mt)
        #pragma unroll
        for (int nt = 0; nt < 2; ++nt)
            #pragma unroll
            for (int r = 0; r < 4; ++r) {
                const float orv = (orh[mt][nt][r] + orl[mt][nt][r] * IL) * SP;
                const float oiv = (oih[mt][nt][r] + oil[mt][nt][r] * IL) * SP;
                const int q  = q0 + wm * 32 + mt * 16 + g * 4 + r;
                const int dk = wn * 32 + nt * 16 + lr;
                const size_t addr = ((size_t)b * SEQ + q) * DIM + h * DHEAD + dk;
                _Float16 hh = (_Float16)orv;
                XOhr[addr] = hh;
                XOlr[addr] = (_Float16)((orv - (float)hh) * 2048.0f);
                hh = (_Float16)oiv;
                XOhi[addr] = hh;
                XOli[addr] = (_Float16)((oiv - (float)hh) * 2048.0f);
            }
}

// ---------------------------------------------------------------------------
// ComplexLayerNorm elementwise pass
// ---------------------------------------------------------------------------
__global__ __launch_bounds__(256)
void ln_kernel(const float* __restrict__ xr, const float* __restrict__ xi,
               const float* __restrict__ msum, const float* __restrict__ gamma,
               const float* __restrict__ beta,
               float* __restrict__ yr, float* __restrict__ yi)
{
    const int gid = blockIdx.x * 256 + threadIdx.x;
    const int flat = gid << 2;
    const int b = flat >> 20;
    const int d = flat & (DIM - 1);
    const float mr = msum[2*b+0] * (1.0f/1048576.0f);
    const float mi = msum[2*b+1] * (1.0f/1048576.0f);
    const float4 vr = *(const float4*)(xr + flat);
    const float4 vi = *(const float4*)(xi + flat);
    const float4 g  = *(const float4*)(gamma + d);
    const float4 bt = *(const float4*)(beta + d);
    float4 or4, oi4;
    {
        float cr = vr.x - mr, ci = vi.x - mi;
        float inv = 1.0f / sqrtf(cr*cr + ci*ci + 1e-6f);
        or4.x = g.x * (cr * inv) + bt.x; oi4.x = g.x * (ci * inv);
    }
    {
        float cr = vr.y - mr, ci = vi.y - mi;
        float inv = 1.0f / sqrtf(cr*cr + ci*ci + 1e-6f);
        or4.y = g.y * (cr * inv) + bt.y; oi4.y = g.y * (ci * inv);
    }
    {
        float cr = vr.z - mr, ci = vi.z - mi;
        float inv = 1.0f / sqrtf(cr*cr + ci*ci + 1e-6f);
        or4.z = g.z * (cr * inv) + bt.z; oi4.z = g.z * (ci * inv);
    }
    {
        float cr = vr.w - mr, ci = vi.w - mi;
        float inv = 1.0f / sqrtf(cr*cr + ci*ci + 1e-6f);
        or4.w = g.w * (cr * inv) + bt.w; oi4.w = g.w * (ci * inv);
    }
    *(float4*)(yr + flat) = or4;
    *(float4*)(yi + flat) = oi4;
}

// ---------------------------------------------------------------------------
extern "C" void kernel_launch(void* const* d_in, const int* in_sizes, int n_in,
                              void* d_out, int out_size, void* d_ws, size_t ws_size,
                              hipStream_t stream)
{
    const float* q_r   = (const float*)d_in[0];
    const float* q_i   = (const float*)d_in[1];
    const float* k_r   = (const float*)d_in[2];
    const float* k_i   = (const float*)d_in[3];
    const float* v_r   = (const float*)d_in[4];
    const float* v_i   = (const float*)d_in[5];
    const float* wq_r  = (const float*)d_in[6];
    const float* wq_i  = (const float*)d_in[7];
    const float* wk_r  = (const float*)d_in[8];
    const float* wk_i  = (const float*)d_in[9];
    const float* wv_r  = (const float*)d_in[10];
    const float* wv_i  = (const float*)d_in[11];
    const float* wfc_r = (const float*)d_in[12];
    const float* wfc_i = (const float*)d_in[13];
    const float* gamma = (const float*)d_in[14];
    const float* beta  = (const float*)d_in[15];

    float* ws = (float*)d_ws;
    const size_t BUF = BUFN;
    float* QR   = ws + 0*BUF;
    float* QI   = ws + 1*BUF;
    float* KR   = ws + 2*BUF;
    float* KI   = ws + 3*BUF;
    float* VR   = ws + 4*BUF;
    float* VI   = ws + 5*BUF;
    float* MSUM = ws + 6*BUF;
    float* LBUF = ws + 6*BUF + 16;
    _Float16* F  = (_Float16*)(ws + 6*BUF + 16 + 65536);
    _Float16* XS = F;                 // 4 x BUF f16 (cgemm A-side / fc input)
    _Float16* VT = F + 4*BUF;         // 4 x BUF f16 (V^T split)
    _Float16* WSp = F + 8*BUF;        // 16 x WHN f16 (weight splits)
    float* XR = QR;
    float* XI = QI;

    float* yr   = (float*)d_out;
    float* yi   = yr + BUF;
    float* attn = yr + 2*BUF;

    const dim3 blk(256);
    const dim3 g_gemm(64, 16);
    const float IWS = 1.0f / 64.0f;

    splitw_kernel<<<dim3(1024, 8), blk, 0, stream>>>(wq_r, wq_i, wk_r, wk_i,
                                                     wv_r, wv_i, wfc_r, wfc_i, WSp);

    splitx_kernel<<<dim3(4096, 2), blk, 0, stream>>>(q_r, q_i, XS);
    cgemm16_kernel<0><<<g_gemm, blk, 0, stream>>>(
        XS + 0*BUF, XS + 1*BUF, XS + 2*BUF, XS + 3*BUF,
        WSp + 0*WHN, WSp + 1*WHN, WSp + 2*WHN, WSp + 3*WHN,
        QR, QI, nullptr, nullptr, nullptr, 0.125f * IWS);

    splitx_kernel<<<dim3(4096, 2), blk, 0, stream>>>(k_r, k_i, XS);
    cgemm16_kernel<0><<<g_gemm, blk, 0, stream>>>(
        XS + 0*BUF, XS + 1*BUF, XS + 2*BUF, XS + 3*BUF,
        WSp + 4*WHN, WSp + 5*WHN, WSp + 6*WHN, WSp + 7*WHN,
        KR, KI, nullptr, nullptr, nullptr, IWS);

    splitx_kernel<<<dim3(4096, 2), blk, 0, stream>>>(v_r, v_i, XS);
    cgemm16_kernel<0><<<g_gemm, blk, 0, stream>>>(
        XS + 0*BUF, XS + 1*BUF, XS + 2*BUF, XS + 3*BUF,
        WSp + 8*WHN, WSp + 9*WHN, WSp + 10*WHN, WSp + 11*WHN,
        VR, VI, nullptr, nullptr, nullptr, IWS);

    vtrans_kernel<<<dim3(16, 64), blk, 0, stream>>>(VR, VI,
        VT + 0*BUF, VT + 1*BUF, VT + 2*BUF, VT + 3*BUF);

    attn_scores_kernel<<<dim3(16, 64), blk, 0, stream>>>(QR, QI, KR, KI, attn, LBUF);

    attn_pv_kernel<<<dim3(16, 64), blk, 0, stream>>>(attn, LBUF,
        VT + 0*BUF, VT + 1*BUF, VT + 2*BUF, VT + 3*BUF,
        XS + 0*BUF, XS + 1*BUF, XS + 2*BUF, XS + 3*BUF);

    hipMemsetAsync(MSUM, 0, 8 * sizeof(float), stream);
    cgemm16_kernel<1><<<g_gemm, blk, 0, stream>>>(
        XS + 0*BUF, XS + 1*BUF, XS + 2*BUF, XS + 3*BUF,
        WSp + 12*WHN, WSp + 13*WHN, WSp + 14*WHN, WSp + 15*WHN,
        XR, XI, q_r, q_i, MSUM, IWS);
    ln_kernel<<<dim3(4096), blk, 0, stream>>>(XR, XI, MSUM, gamma, beta, yr, yi);
}